// Round 3
// baseline (782.287 us; speedup 1.0000x reference)
//
#include <hip/hip_runtime.h>
#include <stdint.h>

#define N_NODES 200000

typedef unsigned short u16;
typedef __attribute__((ext_vector_type(8))) short short8;
typedef __attribute__((ext_vector_type(4))) float floatx4;

__device__ inline float bf2f(u16 u) {
  union { uint32_t i; float f; } v; v.i = ((uint32_t)u) << 16; return v.f;
}
__device__ inline u16 f2bf(float f) {
  union { float f; uint32_t i; } v; v.f = f;
  uint32_t lsb = (v.i >> 16) & 1u;
  return (u16)((v.i + 0x7fffu + lsb) >> 16);
}

// ---------------------------------------------------------------------------
// WS budget note: R1 proved ws_size >= 51,492,864 B. R2 used 51,507,456 B and
// showed persistent-state corruption (OOB write past ws). This layout's
// high-water mark is 51,488,768 B. G/cs/ac3 alias the dead w1t region.
// ---------------------------------------------------------------------------

// prep: zero small stat area; transpose+cast weights to bf16 B-layout
//   w1t[n][k] (64x256), w2t[kn][n][k] (27x64x64), w3t[n][k] (256x64)
__global__ void prep_kernel(const float* __restrict__ W1, const float* __restrict__ W2,
                            const float* __restrict__ W3,
                            u16* __restrict__ w1t, u16* __restrict__ w2t,
                            u16* __restrict__ w3t, float* __restrict__ fl) {
  int tid = blockIdx.x * blockDim.x + threadIdx.x;
  int nth = gridDim.x * blockDim.x;
  for (int i = tid; i < 512; i += nth) fl[i] = 0.f;
  for (int i = tid; i < 256 * 64; i += nth) {        // w1t[n*256+k] = W1[k][n]
    int n = i >> 8, k = i & 255;
    w1t[i] = f2bf(W1[k * 64 + n]);
  }
  for (int i = tid; i < 27 * 64 * 64; i += nth) {    // w2t[kn][n][k] = W2[kn][k][n]
    int kn = i >> 12, r = i & 4095, n = r >> 6, k = r & 63;
    w2t[i] = f2bf(W2[kn * 4096 + k * 64 + n]);
  }
  for (int i = tid; i < 256 * 64; i += nth) {        // w3t[n*64+k] = W3[k][n]
    int n = i >> 6, k = i & 63;
    w3t[i] = f2bf(W3[k * 256 + n]);
  }
}

// ---------------------------------------------------------------------------
// gemm1: y1[N,64] raw bf16 = bf16(x[N,256]) @ W1; fused per-channel stats.
// ---------------------------------------------------------------------------
__global__ __launch_bounds__(256) void gemm1_kernel(const float* __restrict__ x,
                                                    const u16* __restrict__ w1t,
                                                    u16* __restrict__ y1,
                                                    float* __restrict__ s1) {
  __shared__ float ps[4][64], pq[4][64];
  int t = threadIdx.x, w = t >> 6, lane = t & 63, m = lane & 15, q = lane >> 4;
  long long rowA = (long long)blockIdx.x * 64 + w * 16 + m;
  const float* xr = x + rowA * 256 + q * 8;
  floatx4 acc[4] = {};
  #pragma unroll
  for (int kc = 0; kc < 8; kc++) {
    floatx4 v0 = *(const floatx4*)(xr + kc * 32);
    floatx4 v1 = *(const floatx4*)(xr + kc * 32 + 4);
    short8 af;
    af[0] = f2bf(v0[0]); af[1] = f2bf(v0[1]); af[2] = f2bf(v0[2]); af[3] = f2bf(v0[3]);
    af[4] = f2bf(v1[0]); af[5] = f2bf(v1[1]); af[6] = f2bf(v1[2]); af[7] = f2bf(v1[3]);
    #pragma unroll
    for (int tt = 0; tt < 4; tt++) {
      short8 bf = *(const short8*)(w1t + (tt * 16 + m) * 256 + kc * 32 + q * 8);
      acc[tt] = __builtin_amdgcn_mfma_f32_16x16x32_bf16(af, bf, acc[tt], 0, 0, 0);
    }
  }
  long long rowC = (long long)blockIdx.x * 64 + w * 16 + q * 4;
  #pragma unroll
  for (int tt = 0; tt < 4; tt++) {
    float s = 0.f, sq = 0.f;
    #pragma unroll
    for (int r = 0; r < 4; r++) {
      float v = acc[tt][r];
      s += v; sq += v * v;
      y1[(rowC + r) * 64 + tt * 16 + m] = f2bf(v);
    }
    s += __shfl_xor(s, 16); s += __shfl_xor(s, 32);
    sq += __shfl_xor(sq, 16); sq += __shfl_xor(sq, 32);
    if (q == 0) { ps[w][tt * 16 + m] = s; pq[w][tt * 16 + m] = sq; }
  }
  __syncthreads();
  if (t < 64) {
    float S = ps[0][t] + ps[1][t] + ps[2][t] + ps[3][t];
    float Q = pq[0][t] + pq[1][t] + pq[2][t] + pq[3][t];
    atomicAdd(&s1[t], S);
    atomicAdd(&s1[64 + t], Q);
  }
}

// fold BN into affine (ac[c]=a, ac[C+c]=c); also zero zn floats at zp
// (used to clear G/cs, which alias the dead w1t region, before gram runs)
__global__ void finalize_kernel(const float* __restrict__ sums, const float* __restrict__ g,
                                const float* __restrict__ b, float* __restrict__ ac, int C,
                                float* __restrict__ zp, int zn) {
  int t = threadIdx.x;
  for (int i = t; i < zn; i += blockDim.x) zp[i] = 0.f;
  if (t < C) {
    float inv = 1.f / (float)N_NODES;
    float mean = sums[t] * inv;
    float var = sums[C + t] * inv - mean * mean;
    float a = g[t] * rsqrtf(var + 1e-3f);
    ac[t] = a;
    ac[C + t] = b[t] - mean * a;
  }
}

// in-place bf16 BN+ReLU for y1 (C=64)
__global__ __launch_bounds__(256) void apply_bn_relu_kernel(u16* __restrict__ y,
                                                            const float* __restrict__ ac) {
  __shared__ float a[64], cc[64];
  int t = threadIdx.x;
  if (t < 64) { a[t] = ac[t]; cc[t] = ac[64 + t]; }
  __syncthreads();
  const long long total = (long long)N_NODES * 64 / 8;
  for (long long i = (long long)blockIdx.x * 256 + t; i < total;
       i += (long long)gridDim.x * 256) {
    uint4 u = ((uint4*)y)[i];
    int c0 = (int)((i & 7) * 8);
    u16* us = (u16*)&u;
    #pragma unroll
    for (int j = 0; j < 8; j++) {
      float v = fmaf(a[c0 + j], bf2f(us[j]), cc[c0 + j]);
      us[j] = f2bf(fmaxf(v, 0.f));
    }
    ((uint4*)y)[i] = u;
  }
}

// ---------------------------------------------------------------------------
// gemm2: y2[N,64] raw bf16 = gather(h1, neigh) . W2; fused stats.
// 256-row blocks (782), barrier-free K-loop.
// ---------------------------------------------------------------------------
__global__ __launch_bounds__(256) void gemm2_kernel(const u16* __restrict__ h1,
                                                    const int* __restrict__ neigh,
                                                    const u16* __restrict__ w2t,
                                                    u16* __restrict__ y2,
                                                    float* __restrict__ s2) {
  __shared__ int nidx[256 * 27];
  __shared__ float ps[4][64], pq[4][64];
  int t = threadIdx.x;
  long long rowBase = (long long)blockIdx.x * 256;
  int limit = (int)((N_NODES - rowBase) * 27); if (limit > 6912) limit = 6912;
  #pragma unroll
  for (int j = 0; j < 27; j++) {
    int lin = j * 256 + t;
    nidx[lin] = (lin < limit) ? neigh[rowBase * 27 + lin] : 0;
  }
  __syncthreads();
  int w = t >> 6, lane = t & 63, m = lane & 15, q = lane >> 4;
  int rA[4]; bool vA[4];
  #pragma unroll
  for (int mt = 0; mt < 4; mt++) {
    rA[mt] = w * 64 + mt * 16 + m;
    vA[mt] = (rowBase + rA[mt]) < N_NODES;
  }
  floatx4 acc[4][4] = {};
  for (int k = 0; k < 27; k++) {
    #pragma unroll
    for (int kc = 0; kc < 2; kc++) {
      short8 af[4];
      #pragma unroll
      for (int mt = 0; mt < 4; mt++) {
        int idx = nidx[rA[mt] * 27 + k];
        uint4 u = *((const uint4*)(h1 + (long long)idx * 64 + kc * 32 + q * 8));
        if (!vA[mt]) { u.x = 0u; u.y = 0u; u.z = 0u; u.w = 0u; }
        af[mt] = *(short8*)&u;
      }
      #pragma unroll
      for (int tt = 0; tt < 4; tt++) {
        short8 bf = *(const short8*)(w2t + k * 4096 + (tt * 16 + m) * 64 + kc * 32 + q * 8);
        #pragma unroll
        for (int mt = 0; mt < 4; mt++)
          acc[mt][tt] = __builtin_amdgcn_mfma_f32_16x16x32_bf16(af[mt], bf, acc[mt][tt], 0, 0, 0);
      }
    }
  }
  #pragma unroll
  for (int tt = 0; tt < 4; tt++) {
    float s = 0.f, sq = 0.f;
    #pragma unroll
    for (int mt = 0; mt < 4; mt++) {
      long long rowC = rowBase + w * 64 + mt * 16 + q * 4;
      #pragma unroll
      for (int r = 0; r < 4; r++) {
        float v = acc[mt][tt][r];
        s += v; sq += v * v;
        if (rowC + r < N_NODES) y2[(rowC + r) * 64 + tt * 16 + m] = f2bf(v);
      }
    }
    s += __shfl_xor(s, 16); s += __shfl_xor(s, 32);
    sq += __shfl_xor(sq, 16); sq += __shfl_xor(sq, 32);
    if (q == 0) { ps[w][tt * 16 + m] = s; pq[w][tt * 16 + m] = sq; }
  }
  __syncthreads();
  if (t < 64) {
    float S = ps[0][t] + ps[1][t] + ps[2][t] + ps[3][t];
    float Q = pq[0][t] + pq[1][t] + pq[2][t] + pq[3][t];
    atomicAdd(&s2[t], S);
    atomicAdd(&s2[64 + t], Q);
  }
}

// ---------------------------------------------------------------------------
// gram: G = h2^T h2 (64x64) and cs = colsum(h2), h2 = relu(bn2(y2)) on the fly
// ---------------------------------------------------------------------------
__global__ __launch_bounds__(256) void gram_kernel(const u16* __restrict__ y2,
                                                   const float* __restrict__ ac2,
                                                   float* __restrict__ G,
                                                   float* __restrict__ cs) {
  __shared__ float T[64][130];
  __shared__ float sld[64];
  int t = threadIdx.x;
  if (t < 64) sld[t] = 0.f;
  __syncthreads();
  long long nodeBase = (long long)blockIdx.x * 128;
  int ch0 = (t & 7) * 8;
  float av[8], cv[8];
  #pragma unroll
  for (int j = 0; j < 8; j++) { av[j] = ac2[ch0 + j]; cv[j] = ac2[64 + ch0 + j]; }
  float myS[8] = {};
  #pragma unroll
  for (int i = 0; i < 4; i++) {
    int node = i * 32 + (t >> 3);
    long long gn = nodeBase + node;
    uint4 u = {0u, 0u, 0u, 0u};
    bool valid = gn < N_NODES;
    if (valid) u = *((const uint4*)(y2 + gn * 64) + (t & 7));
    u16* us = (u16*)&u;
    #pragma unroll
    for (int j = 0; j < 8; j++) {
      float v = valid ? fmaxf(fmaf(av[j], bf2f(us[j]), cv[j]), 0.f) : 0.f;
      T[ch0 + j][node] = v;
      myS[j] += v;
    }
  }
  #pragma unroll
  for (int j = 0; j < 8; j++) atomicAdd(&sld[ch0 + j], myS[j]);
  __syncthreads();
  int w = t >> 6, lane = t & 63, m = lane & 15, q = lane >> 4;
  floatx4 gacc[4] = {};
  #pragma unroll
  for (int kc = 0; kc < 4; kc++) {
    short8 af;
    #pragma unroll
    for (int j = 0; j < 8; j++) af[j] = f2bf(T[w * 16 + m][kc * 32 + q * 8 + j]);
    #pragma unroll
    for (int nt = 0; nt < 4; nt++) {
      short8 bf;
      #pragma unroll
      for (int j = 0; j < 8; j++) bf[j] = f2bf(T[nt * 16 + m][kc * 32 + q * 8 + j]);
      gacc[nt] = __builtin_amdgcn_mfma_f32_16x16x32_bf16(af, bf, gacc[nt], 0, 0, 0);
    }
  }
  #pragma unroll
  for (int nt = 0; nt < 4; nt++)
    #pragma unroll
    for (int r = 0; r < 4; r++)
      atomicAdd(&G[(w * 16 + q * 4 + r) * 64 + nt * 16 + m], gacc[nt][r]);
  if (t < 64) atomicAdd(&cs[t], sld[t]);
}

// ---------------------------------------------------------------------------
// finalize3: BN3 affine from Gram.  mean_c = cs.W3[:,c]/N;
// sumsq_c = W3[:,c]^T G W3[:,c].  256 blocks x 64 threads.
// ---------------------------------------------------------------------------
__global__ void finalize3_kernel(const float* __restrict__ G, const float* __restrict__ cs,
                                 const float* __restrict__ W3, const float* __restrict__ g3,
                                 const float* __restrict__ b3, float* __restrict__ ac3) {
  __shared__ float Gl[64 * 65];
  __shared__ float wc[64];
  int j = threadIdx.x;
  int c = blockIdx.x;
  for (int i = 0; i < 64; i++) Gl[i * 65 + j] = G[i * 64 + j];
  wc[j] = W3[j * 256 + c];
  __syncthreads();
  float wjc = wc[j];
  float mj = 0.f;
  #pragma unroll 8
  for (int k = 0; k < 64; k++) mj = fmaf(Gl[j * 65 + k], wc[k], mj);
  float p = wjc * mj;
  float ms = cs[j] * wjc;
  #pragma unroll
  for (int off = 32; off > 0; off >>= 1) { p += __shfl_xor(p, off); ms += __shfl_xor(ms, off); }
  if (j == 0) {
    float inv = 1.f / (float)N_NODES;
    float mean = ms * inv;
    float var = p * inv - mean * mean;
    float a = g3[c] * rsqrtf(var + 1e-3f);
    ac3[c] = a;
    ac3[256 + c] = b3[c] - mean * a;
  }
}

// ---------------------------------------------------------------------------
// gemm3 (fully fused): out = relu( bn3( relu(bn2(y2)) @ W3 ) + x ), fp32 out.
// ---------------------------------------------------------------------------
__global__ __launch_bounds__(256) void gemm3_kernel(const u16* __restrict__ y2,
                                                    const float* __restrict__ ac2,
                                                    const u16* __restrict__ w3t,
                                                    const float* __restrict__ x,
                                                    const float* __restrict__ ac3,
                                                    float* __restrict__ out) {
  int t = threadIdx.x, w = t >> 6, lane = t & 63, m = lane & 15, q = lane >> 4;
  long long rowBase = (long long)blockIdx.x * 64;
  floatx4 acc[4][4] = {};
  #pragma unroll
  for (int kc = 0; kc < 2; kc++) {
    float a2v[8], c2v[8];
    #pragma unroll
    for (int j = 0; j < 8; j++) {
      a2v[j] = ac2[kc * 32 + q * 8 + j];
      c2v[j] = ac2[64 + kc * 32 + q * 8 + j];
    }
    short8 af[4];
    #pragma unroll
    for (int mt = 0; mt < 4; mt++) {
      long long row = rowBase + mt * 16 + m;
      uint4 u = *((const uint4*)(y2 + row * 64 + kc * 32 + q * 8));
      u16* us = (u16*)&u;
      #pragma unroll
      for (int j = 0; j < 8; j++)
        af[mt][j] = f2bf(fmaxf(fmaf(a2v[j], bf2f(us[j]), c2v[j]), 0.f));
    }
    #pragma unroll
    for (int tt = 0; tt < 4; tt++) {
      short8 bf = *(const short8*)(w3t + (w * 64 + tt * 16 + m) * 64 + kc * 32 + q * 8);
      #pragma unroll
      for (int mt = 0; mt < 4; mt++)
        acc[mt][tt] = __builtin_amdgcn_mfma_f32_16x16x32_bf16(af[mt], bf, acc[mt][tt], 0, 0, 0);
    }
  }
  #pragma unroll
  for (int tt = 0; tt < 4; tt++) {
    int col = w * 64 + tt * 16 + m;
    float a3v = ac3[col], c3v = ac3[256 + col];
    #pragma unroll
    for (int mt = 0; mt < 4; mt++) {
      long long row = rowBase + mt * 16 + q * 4;
      #pragma unroll
      for (int r = 0; r < 4; r++) {
        float v = fmaf(a3v, acc[mt][tt][r], c3v) + x[(row + r) * 256 + col];
        out[(row + r) * 256 + col] = fmaxf(v, 0.f);
      }
    }
  }
}

// ---------------------------------------------------------------------------
extern "C" void kernel_launch(void* const* d_in, const int* in_sizes, int n_in,
                              void* d_out, int out_size, void* d_ws, size_t ws_size,
                              hipStream_t stream) {
  (void)in_sizes; (void)n_in; (void)out_size; (void)ws_size;
  const float* x   = (const float*)d_in[0];
  const int* neigh = (const int*)d_in[1];
  const float* W1  = (const float*)d_in[3];
  const float* g1  = (const float*)d_in[4];
  const float* b1  = (const float*)d_in[5];
  const float* W2  = (const float*)d_in[6];
  const float* g2  = (const float*)d_in[7];
  const float* b2  = (const float*)d_in[8];
  const float* W3  = (const float*)d_in[9];
  const float* g3  = (const float*)d_in[10];
  const float* b3  = (const float*)d_in[11];

  char* ws = (char*)d_ws;
  u16* y1  = (u16*)(ws);                       // [0, 25,600,000)
  u16* y2  = (u16*)(ws + 25600000LL);          // [25.6M, 51.2M)
  // aux region [51,200,000, 51,232,768): w1t first; G/cs/ac3 alias it after
  // gemm1 is done (w1t dead from dispatch 3 onward).
  u16* w1t   = (u16*)(ws + 51200000LL);        // 32,768 B
  float* G   = (float*)(ws + 51200000LL);      // 4096 floats
  float* cs  = G + 4096;                       // 64 floats
  float* ac3 = G + 4160;                       // 512 floats (ends at +18,688 B)
  u16* w2t = (u16*)(ws + 51232768LL);          // 221,184 B
  u16* w3t = (u16*)(ws + 51453952LL);          // 32,768 B
  float* fl = (float*)(ws + 51486720LL);       // 512 floats -> end 51,488,768
  float* s1  = fl;        float* ac1 = fl + 128;
  float* s2  = fl + 256;  float* ac2 = fl + 384;
  float* out = (float*)d_out;

  prep_kernel<<<256, 256, 0, stream>>>(W1, W2, W3, w1t, w2t, w3t, fl);

  gemm1_kernel<<<3125, 256, 0, stream>>>(x, w1t, y1, s1);
  finalize_kernel<<<1, 256, 0, stream>>>(s1, g1, b1, ac1, 64, s1, 0);
  apply_bn_relu_kernel<<<2048, 256, 0, stream>>>(y1, ac1);   // y1 -> h1 in place

  gemm2_kernel<<<782, 256, 0, stream>>>(y1, neigh, w2t, y2, s2);
  // finalize BN2 and zero G+cs (4160 floats; w1t region is dead now)
  finalize_kernel<<<1, 256, 0, stream>>>(s2, g2, b2, ac2, 64, G, 4160);

  gram_kernel<<<1563, 256, 0, stream>>>(y2, ac2, G, cs);
  finalize3_kernel<<<256, 64, 0, stream>>>(G, cs, W3, g3, b3, ac3);

  gemm3_kernel<<<3125, 256, 0, stream>>>(y2, ac2, w3t, x, ac3, out);
}